// Round 1
// baseline (1535.658 us; speedup 1.0000x reference)
//
#include <hip/hip_runtime.h>
#include <math.h>

#define NN 50000
#define EE 800000
#define HIDF 128
#define NHEAD 8
#define OUTF 32
#define BN_EPS 1e-5f

// ---------------------------------------------------------------------------
// GEMM: C[M,NC] = A[M,KDIM] @ B[KDIM,NC] (+ resid elementwise if non-null)
// 256 threads, block tile 128 rows x NC cols, micro-tile 8 x TN per thread.
// A staged transposed in LDS so inner-loop a-reads are broadcast float4s.
// ---------------------------------------------------------------------------
template<int KDIM, int NC, int TN>
__global__ __launch_bounds__(256)
void gemm_k(const float* __restrict__ A, const float* __restrict__ B,
            const float* __restrict__ resid, float* __restrict__ C, int M) {
  constexpr int BM = 128, BK = 32;
  __shared__ float As[BK][BM + 4];   // [k][row], +4 pad keeps rows 16B aligned
  __shared__ float Bs[BK][NC + 4];
  const int tid = threadIdx.x;
  const int tx = tid & 15, ty = tid >> 4;
  const int row0 = blockIdx.x * BM;
  float acc[8][TN];
#pragma unroll
  for (int i = 0; i < 8; ++i)
#pragma unroll
    for (int j = 0; j < TN; ++j) acc[i][j] = 0.f;

  const int kq = tid & 7, rr = tid >> 3;

  for (int k0 = 0; k0 < KDIM; k0 += BK) {
    // stage A tile (128x32) with transpose: global read coalesced along k
#pragma unroll
    for (int i = 0; i < 4; ++i) {
      int r = rr + i * 32;
      int gr = row0 + r;
      float4 v = make_float4(0.f, 0.f, 0.f, 0.f);
      if (gr < M) v = *(const float4*)(A + (size_t)gr * KDIM + k0 + kq * 4);
      As[kq * 4 + 0][r] = v.x; As[kq * 4 + 1][r] = v.y;
      As[kq * 4 + 2][r] = v.z; As[kq * 4 + 3][r] = v.w;
    }
    // stage B tile (32 x NC), fully coalesced float4
    {
      constexpr int C4 = NC / 4;
      constexpr int PER = (BK * NC) / (256 * 4);
      int bk = tid / C4, bc = tid % C4;
#pragma unroll
      for (int i = 0; i < PER; ++i) {
        int kk = bk + i * (256 / C4);
        *(float4*)&Bs[kk][bc * 4] =
            *(const float4*)(B + (size_t)(k0 + kk) * NC + bc * 4);
      }
    }
    __syncthreads();
#pragma unroll
    for (int k = 0; k < BK; ++k) {
      float a[8];
      *(float4*)&a[0] = *(const float4*)&As[k][ty * 8];
      *(float4*)&a[4] = *(const float4*)&As[k][ty * 8 + 4];
      float b[TN];
      if constexpr (TN == 8) {
        *(float4*)&b[0] = *(const float4*)&Bs[k][tx * 8];
        *(float4*)&b[4] = *(const float4*)&Bs[k][tx * 8 + 4];
      } else {
#pragma unroll
        for (int j = 0; j < TN; ++j) b[j] = Bs[k][tx * TN + j];
      }
#pragma unroll
      for (int i = 0; i < 8; ++i)
#pragma unroll
        for (int j = 0; j < TN; ++j) acc[i][j] += a[i] * b[j];
    }
    __syncthreads();
  }
#pragma unroll
  for (int i = 0; i < 8; ++i) {
    int gr = row0 + ty * 8 + i;
    if (gr >= M) continue;
    size_t base = (size_t)gr * NC + tx * TN;
    if (resid) {
#pragma unroll
      for (int j = 0; j < TN; ++j) acc[i][j] += resid[base + j];
    }
#pragma unroll
    for (int j = 0; j < TN; ++j) C[base + j] = acc[i][j];
  }
}

// ---------------------------------------------------------------------------
// BatchNorm: column sums/sumsq -> scale/shift, then apply+relu
// ---------------------------------------------------------------------------
__global__ __launch_bounds__(256)
void bn_stats_k(const float* __restrict__ Y, float* __restrict__ stats, int M) {
  __shared__ float sh[256], sq[256];
  int col = threadIdx.x & 127;
  int half = threadIdx.x >> 7;
  int start = blockIdx.x * 64;
  int end = min(start + 64, M);
  float s = 0.f, q = 0.f;
  for (int r = start + half; r < end; r += 2) {
    float v = Y[(size_t)r * 128 + col];
    s += v; q += v * v;
  }
  sh[threadIdx.x] = s; sq[threadIdx.x] = q;
  __syncthreads();
  if (half == 0) {
    s = sh[threadIdx.x] + sh[threadIdx.x + 128];
    q = sq[threadIdx.x] + sq[threadIdx.x + 128];
    atomicAdd(&stats[col], s);
    atomicAdd(&stats[128 + col], q);
  }
}

__global__ void bn_final_k(float* stats, const float* __restrict__ gamma,
                           const float* __restrict__ beta) {
  int c = threadIdx.x;  // 128 threads
  float mean = stats[c] * (1.f / NN);
  float var = stats[128 + c] * (1.f / NN) - mean * mean;
  var = fmaxf(var, 0.f);
  float sc = gamma[c] * rsqrtf(var + BN_EPS);
  stats[256 + c] = sc;
  stats[384 + c] = beta[c] - mean * sc;
}

__global__ __launch_bounds__(256)
void bn_apply_k(const float* __restrict__ Y, const float* __restrict__ stats,
                float* __restrict__ H, int M) {
  size_t i = (size_t)blockIdx.x * 256 + threadIdx.x;  // over M*32 float4s
  if (i >= (size_t)M * 32) return;
  int c4 = (int)(i & 31) * 4;
  float4 y = ((const float4*)Y)[i];
  float4 h;
  h.x = fmaxf(y.x * stats[256 + c4 + 0] + stats[384 + c4 + 0], 0.f);
  h.y = fmaxf(y.y * stats[256 + c4 + 1] + stats[384 + c4 + 1], 0.f);
  h.z = fmaxf(y.z * stats[256 + c4 + 2] + stats[384 + c4 + 2], 0.f);
  h.w = fmaxf(y.w * stats[256 + c4 + 3] + stats[384 + c4 + 3], 0.f);
  ((float4*)H)[i] = h;
}

// ---------------------------------------------------------------------------
// attention logits el/er per (node, head)
// ---------------------------------------------------------------------------
__global__ __launch_bounds__(256)
void eler_k(const float* __restrict__ feat, const float* __restrict__ al,
            const float* __restrict__ ar, float* __restrict__ el,
            float* __restrict__ er) {
  int i = blockIdx.x * 256 + threadIdx.x;  // over N*8
  if (i >= NN * NHEAD) return;
  int h = i & 7;
  const float4* f4 = (const float4*)(feat + (size_t)i * 16);
  const float4* l4 = (const float4*)(al + h * 16);
  const float4* r4 = (const float4*)(ar + h * 16);
  float sl = 0.f, sr = 0.f;
#pragma unroll
  for (int q = 0; q < 4; ++q) {
    float4 f = f4[q], a = l4[q], b = r4[q];
    sl += f.x * a.x + f.y * a.y + f.z * a.z + f.w * a.w;
    sr += f.x * b.x + f.y * b.y + f.z * b.z + f.w * b.w;
  }
  el[i] = sl; er[i] = sr;
}

// ---------------------------------------------------------------------------
// CSR build: histogram, block scan, scan of block sums, add offsets, fill
// ---------------------------------------------------------------------------
__global__ __launch_bounds__(256)
void hist_k(const int* __restrict__ dst, int* __restrict__ deg) {
  int e = blockIdx.x * 256 + threadIdx.x;
  if (e < EE) atomicAdd(&deg[dst[e]], 1);
}

__global__ __launch_bounds__(256)
void scan_block_k(const int* __restrict__ in, int* __restrict__ out,
                  int* __restrict__ bsums, int n) {
  __shared__ int sh[256];
  int i = blockIdx.x * 256 + threadIdx.x;
  int v = (i < n) ? in[i] : 0;
  sh[threadIdx.x] = v;
  __syncthreads();
#pragma unroll
  for (int off = 1; off < 256; off <<= 1) {
    int t = (threadIdx.x >= off) ? sh[threadIdx.x - off] : 0;
    __syncthreads();
    sh[threadIdx.x] += t;
    __syncthreads();
  }
  if (i < n) out[i] = sh[threadIdx.x] - v;  // exclusive
  if (threadIdx.x == 255) bsums[blockIdx.x] = sh[255];
}

__global__ __launch_bounds__(256)
void scan_bsums_k(int* bsums, int nb) {
  __shared__ int sh[256];
  int v = (threadIdx.x < nb) ? bsums[threadIdx.x] : 0;
  sh[threadIdx.x] = v;
  __syncthreads();
#pragma unroll
  for (int off = 1; off < 256; off <<= 1) {
    int t = (threadIdx.x >= off) ? sh[threadIdx.x - off] : 0;
    __syncthreads();
    sh[threadIdx.x] += t;
    __syncthreads();
  }
  if (threadIdx.x < nb) bsums[threadIdx.x] = sh[threadIdx.x] - v;
}

__global__ __launch_bounds__(256)
void add_off_k(int* __restrict__ out, const int* __restrict__ bsums, int n) {
  int i = blockIdx.x * 256 + threadIdx.x;
  if (i < n) out[i] += bsums[blockIdx.x];
  if (i == 0) out[n] = EE;
}

__global__ __launch_bounds__(256)
void fill_k(const int* __restrict__ src, const int* __restrict__ dst,
            const int* __restrict__ rowptr, int* __restrict__ cnt,
            int* __restrict__ csrsrc) {
  int e = blockIdx.x * 256 + threadIdx.x;
  if (e >= EE) return;
  int d = dst[e];
  int p = rowptr[d] + atomicAdd(&cnt[d], 1);
  csrsrc[p] = src[e];
}

// ---------------------------------------------------------------------------
// GAT aggregate: one wave per dst node, online softmax, lane owns 2 features.
// MODE 0: tmp = rst + bias       (relation 0)
// MODE 1: h1 += leaky_relu(tmp + rst + bias, 0.01)   (relation 1 + layer tail)
// ---------------------------------------------------------------------------
template<int MODE>
__global__ __launch_bounds__(256)
void gat_agg_k(const float* __restrict__ feat, const float* __restrict__ el,
               const float* __restrict__ er, const int* __restrict__ rowptr,
               const int* __restrict__ csrsrc, const float* __restrict__ bias,
               float* __restrict__ tmp, float* __restrict__ h1) {
  int n = blockIdx.x * 4 + (threadIdx.x >> 6);
  if (n >= NN) return;
  int lane = threadIdx.x & 63;
  int head = lane >> 3;  // features 2*lane, 2*lane+1 both belong to this head
  float er_h = er[(size_t)n * 8 + head];
  int beg = rowptr[n], end = rowptr[n + 1];
  float m = -INFINITY, lsum = 0.f, a0 = 0.f, a1 = 0.f;
  for (int idx = beg; idx < end; ++idx) {
    int s = csrsrc[idx];
    float e = el[(size_t)s * 8 + head] + er_h;
    e = (e > 0.f) ? e : 0.2f * e;              // leaky_relu 0.2
    float mn = fmaxf(m, e);
    float scl = __expf(m - mn);                // first iter: exp(-inf)=0
    float p = __expf(e - mn);
    float2 f = *(const float2*)(feat + (size_t)s * 128 + lane * 2);
    lsum = lsum * scl + p;
    a0 = a0 * scl + p * f.x;
    a1 = a1 * scl + p * f.y;
    m = mn;
  }
  float inv = (lsum > 0.f) ? 1.f / lsum : 0.f;  // isolated node -> rst = 0
  float r0 = a0 * inv + bias[lane * 2];
  float r1 = a1 * inv + bias[lane * 2 + 1];
  size_t o = (size_t)n * 128 + lane * 2;
  if (MODE == 0) {
    tmp[o] = r0; tmp[o + 1] = r1;
  } else {
    float t0 = tmp[o] + r0, t1 = tmp[o + 1] + r1;
    t0 = (t0 > 0.f) ? t0 : 0.01f * t0;
    t1 = (t1 > 0.f) ? t1 : 0.01f * t1;
    h1[o] += t0; h1[o + 1] += t1;
  }
}

// ---------------------------------------------------------------------------
extern "C" void kernel_launch(void* const* d_in, const int* in_sizes, int n_in,
                              void* d_out, int out_size, void* d_ws,
                              size_t ws_size, hipStream_t stream) {
  const float* inputs = (const float*)d_in[0];
  const int* src = (const int*)d_in[1];
  const int* dst = (const int*)d_in[2];
  const float* ew1 = (const float*)d_in[3];
  const float* eg = (const float*)d_in[4];
  const float* eb = (const float*)d_in[5];
  const float* ew2 = (const float*)d_in[6];
  const float* gfc = (const float*)d_in[7];
  const float* gal = (const float*)d_in[8];
  const float* gar = (const float*)d_in[9];
  const float* gb = (const float*)d_in[10];
  const float* dw1 = (const float*)d_in[11];
  const float* dg = (const float*)d_in[12];
  const float* db = (const float*)d_in[13];
  const float* dw2 = (const float*)d_in[14];
  float* out = (float*)d_out;

  // workspace layout (~87 MB)
  float* h1 = (float*)d_ws;
  float* feat = h1 + (size_t)NN * HIDF;
  float* tmp = feat + (size_t)NN * HIDF;
  float* el = tmp + (size_t)NN * HIDF;
  float* er = el + (size_t)NN * NHEAD;
  float* stats = er + (size_t)NN * NHEAD;  // 512 floats
  int* rowptr0 = (int*)(stats + 512);
  int* rowptr1 = rowptr0 + (NN + 1);
  int* csr0 = rowptr1 + (NN + 1);
  int* csr1 = csr0 + EE;
  int* cnt = csr1 + EE;
  int* bsums = cnt + NN;  // 256 ints
  int* rowptr[2] = {rowptr0, rowptr1};
  int* csr[2] = {csr0, csr1};

  const int SCB = (NN + 255) / 256;   // 196
  const int EGB = (EE + 255) / 256;   // 3125
  const int GB = (NN + 127) / 128;    // 391

  // ---- CSR build per relation (graph is static across layers) ----
  for (int r = 0; r < 2; ++r) {
    hipMemsetAsync(cnt, 0, NN * sizeof(int), stream);
    hist_k<<<EGB, 256, 0, stream>>>(dst + (size_t)r * EE, cnt);
    scan_block_k<<<SCB, 256, 0, stream>>>(cnt, rowptr[r], bsums, NN);
    scan_bsums_k<<<1, 256, 0, stream>>>(bsums, SCB);
    add_off_k<<<SCB, 256, 0, stream>>>(rowptr[r], bsums, NN);
    hipMemsetAsync(cnt, 0, NN * sizeof(int), stream);
    fill_k<<<EGB, 256, 0, stream>>>(src + (size_t)r * EE, dst + (size_t)r * EE,
                                    rowptr[r], cnt, csr[r]);
  }

  // ---- embed MLP: h = relu(bn(x@w1)); h1 = h@w2 + h ----
  gemm_k<64, 128, 8><<<GB, 256, 0, stream>>>(inputs, ew1, nullptr, feat, NN);
  hipMemsetAsync(stats, 0, 512 * sizeof(float), stream);
  bn_stats_k<<<(NN + 63) / 64, 256, 0, stream>>>(feat, stats, NN);
  bn_final_k<<<1, 128, 0, stream>>>(stats, eg, eb);
  bn_apply_k<<<(NN * 32 + 255) / 256, 256, 0, stream>>>(feat, stats, tmp, NN);
  gemm_k<128, 128, 8><<<GB, 256, 0, stream>>>(tmp, ew2, tmp, h1, NN);

  // ---- 4 GAT layers, 2 relations each ----
  for (int l = 0; l < 4; ++l) {
    for (int r = 0; r < 2; ++r) {
      const float* W = gfc + (size_t)(l * 2 + r) * HIDF * HIDF;
      const float* al = gal + (size_t)(l * 2 + r) * HIDF;
      const float* ar = gar + (size_t)(l * 2 + r) * HIDF;
      const float* bi = gb + (size_t)(l * 2 + r) * HIDF;
      gemm_k<128, 128, 8><<<GB, 256, 0, stream>>>(h1, W, nullptr, feat, NN);
      eler_k<<<(NN * 8 + 255) / 256, 256, 0, stream>>>(feat, al, ar, el, er);
      if (r == 0)
        gat_agg_k<0><<<NN / 4, 256, 0, stream>>>(feat, el, er, rowptr[0],
                                                 csr[0], bi, tmp, h1);
      else
        gat_agg_k<1><<<NN / 4, 256, 0, stream>>>(feat, el, er, rowptr[1],
                                                 csr[1], bi, tmp, h1);
    }
  }

  // ---- decision MLP: out = relu(bn(h1@w1)) @ w2 ----
  gemm_k<128, 128, 8><<<GB, 256, 0, stream>>>(h1, dw1, nullptr, feat, NN);
  hipMemsetAsync(stats, 0, 512 * sizeof(float), stream);
  bn_stats_k<<<(NN + 63) / 64, 256, 0, stream>>>(feat, stats, NN);
  bn_final_k<<<1, 128, 0, stream>>>(stats, dg, db);
  bn_apply_k<<<(NN * 32 + 255) / 256, 256, 0, stream>>>(feat, stats, tmp, NN);
  gemm_k<128, 32, 2><<<GB, 256, 0, stream>>>(tmp, dw2, nullptr, out, NN);
}

// Round 2
// 1420.449 us; speedup vs baseline: 1.0811x; 1.0811x over previous
//
#include <hip/hip_runtime.h>
#include <hip/hip_fp16.h>
#include <math.h>

#define NN 50000
#define EE 800000
#define HIDF 128
#define NHEAD 8
#define OUTF 32
#define BN_EPS 1e-5f

// ---------------------------------------------------------------------------
// GEMM: C[M,NC] = A[M,KDIM] @ B[KDIM,NC] (+ resid elementwise if non-null)
// 256 threads, block tile 128 rows x NC cols, micro-tile 8 x TN per thread.
// OUT_T = float or __half (GAT feat path writes fp16 to halve gather bytes).
// ---------------------------------------------------------------------------
__device__ __forceinline__ void store_out(float v, float* p) { *p = v; }
__device__ __forceinline__ void store_out(float v, __half* p) { *p = __float2half(v); }

template<int KDIM, int NC, int TN, typename OUT_T>
__global__ __launch_bounds__(256)
void gemm_k(const float* __restrict__ A, const float* __restrict__ B,
            const float* __restrict__ resid, OUT_T* __restrict__ C, int M) {
  constexpr int BM = 128, BK = 32;
  __shared__ float As[BK][BM + 4];
  __shared__ float Bs[BK][NC + 4];
  const int tid = threadIdx.x;
  const int tx = tid & 15, ty = tid >> 4;
  const int row0 = blockIdx.x * BM;
  float acc[8][TN];
#pragma unroll
  for (int i = 0; i < 8; ++i)
#pragma unroll
    for (int j = 0; j < TN; ++j) acc[i][j] = 0.f;

  const int kq = tid & 7, rr = tid >> 3;

  for (int k0 = 0; k0 < KDIM; k0 += BK) {
#pragma unroll
    for (int i = 0; i < 4; ++i) {
      int r = rr + i * 32;
      int gr = row0 + r;
      float4 v = make_float4(0.f, 0.f, 0.f, 0.f);
      if (gr < M) v = *(const float4*)(A + (size_t)gr * KDIM + k0 + kq * 4);
      As[kq * 4 + 0][r] = v.x; As[kq * 4 + 1][r] = v.y;
      As[kq * 4 + 2][r] = v.z; As[kq * 4 + 3][r] = v.w;
    }
    {
      constexpr int C4 = NC / 4;
      constexpr int PER = (BK * NC) / (256 * 4);
      int bk = tid / C4, bc = tid % C4;
#pragma unroll
      for (int i = 0; i < PER; ++i) {
        int kk = bk + i * (256 / C4);
        *(float4*)&Bs[kk][bc * 4] =
            *(const float4*)(B + (size_t)(k0 + kk) * NC + bc * 4);
      }
    }
    __syncthreads();
#pragma unroll
    for (int k = 0; k < BK; ++k) {
      float a[8];
      *(float4*)&a[0] = *(const float4*)&As[k][ty * 8];
      *(float4*)&a[4] = *(const float4*)&As[k][ty * 8 + 4];
      float b[TN];
      if constexpr (TN == 8) {
        *(float4*)&b[0] = *(const float4*)&Bs[k][tx * 8];
        *(float4*)&b[4] = *(const float4*)&Bs[k][tx * 8 + 4];
      } else {
#pragma unroll
        for (int j = 0; j < TN; ++j) b[j] = Bs[k][tx * TN + j];
      }
#pragma unroll
      for (int i = 0; i < 8; ++i)
#pragma unroll
        for (int j = 0; j < TN; ++j) acc[i][j] += a[i] * b[j];
    }
    __syncthreads();
  }
#pragma unroll
  for (int i = 0; i < 8; ++i) {
    int gr = row0 + ty * 8 + i;
    if (gr >= M) continue;
    size_t base = (size_t)gr * NC + tx * TN;
    if (resid) {
#pragma unroll
      for (int j = 0; j < TN; ++j) acc[i][j] += resid[base + j];
    }
#pragma unroll
    for (int j = 0; j < TN; ++j) store_out(acc[i][j], C + base + j);
  }
}

// ---------------------------------------------------------------------------
// BatchNorm: column sums/sumsq -> scale/shift, then apply+relu (in-place ok)
// ---------------------------------------------------------------------------
__global__ __launch_bounds__(256)
void bn_stats_k(const float* __restrict__ Y, float* __restrict__ stats, int M) {
  __shared__ float sh[256], sq[256];
  int col = threadIdx.x & 127;
  int half = threadIdx.x >> 7;
  int start = blockIdx.x * 64;
  int end = min(start + 64, M);
  float s = 0.f, q = 0.f;
  for (int r = start + half; r < end; r += 2) {
    float v = Y[(size_t)r * 128 + col];
    s += v; q += v * v;
  }
  sh[threadIdx.x] = s; sq[threadIdx.x] = q;
  __syncthreads();
  if (half == 0) {
    s = sh[threadIdx.x] + sh[threadIdx.x + 128];
    q = sq[threadIdx.x] + sq[threadIdx.x + 128];
    atomicAdd(&stats[col], s);
    atomicAdd(&stats[128 + col], q);
  }
}

__global__ void bn_final_k(float* stats, const float* __restrict__ gamma,
                           const float* __restrict__ beta) {
  int c = threadIdx.x;  // 128 threads
  float mean = stats[c] * (1.f / NN);
  float var = stats[128 + c] * (1.f / NN) - mean * mean;
  var = fmaxf(var, 0.f);
  float sc = gamma[c] * rsqrtf(var + BN_EPS);
  stats[256 + c] = sc;
  stats[384 + c] = beta[c] - mean * sc;
}

__global__ __launch_bounds__(256)
void bn_apply_k(const float* __restrict__ Y, const float* __restrict__ stats,
                float* __restrict__ H, int M) {
  size_t i = (size_t)blockIdx.x * 256 + threadIdx.x;  // over M*32 float4s
  if (i >= (size_t)M * 32) return;
  int c4 = (int)(i & 31) * 4;
  float4 y = ((const float4*)Y)[i];
  float4 h;
  h.x = fmaxf(y.x * stats[256 + c4 + 0] + stats[384 + c4 + 0], 0.f);
  h.y = fmaxf(y.y * stats[256 + c4 + 1] + stats[384 + c4 + 1], 0.f);
  h.z = fmaxf(y.z * stats[256 + c4 + 2] + stats[384 + c4 + 2], 0.f);
  h.w = fmaxf(y.w * stats[256 + c4 + 3] + stats[384 + c4 + 3], 0.f);
  ((float4*)H)[i] = h;
}

// ---------------------------------------------------------------------------
// attention logits el/er per (node, head) from fp16 feat
// ---------------------------------------------------------------------------
__global__ __launch_bounds__(256)
void eler_k(const __half2* __restrict__ feat, const float* __restrict__ al,
            const float* __restrict__ ar, float* __restrict__ el,
            float* __restrict__ er) {
  int i = blockIdx.x * 256 + threadIdx.x;  // over N*8
  if (i >= NN * NHEAD) return;
  int h = i & 7;
  const __half2* f2 = feat + (size_t)i * 8;  // 16 halves per (node,head)
  float sl = 0.f, sr = 0.f;
#pragma unroll
  for (int q = 0; q < 8; ++q) {
    float2 f = __half22float2(f2[q]);
    sl += f.x * al[h * 16 + 2 * q] + f.y * al[h * 16 + 2 * q + 1];
    sr += f.x * ar[h * 16 + 2 * q] + f.y * ar[h * 16 + 2 * q + 1];
  }
  el[i] = sl; er[i] = sr;
}

// ---------------------------------------------------------------------------
// CSR build: histogram, block scan, scan of block sums, add offsets, fill
// ---------------------------------------------------------------------------
__global__ __launch_bounds__(256)
void hist_k(const int* __restrict__ dst, int* __restrict__ deg) {
  int e = blockIdx.x * 256 + threadIdx.x;
  if (e < EE) atomicAdd(&deg[dst[e]], 1);
}

__global__ __launch_bounds__(256)
void scan_block_k(const int* __restrict__ in, int* __restrict__ out,
                  int* __restrict__ bsums, int n) {
  __shared__ int sh[256];
  int i = blockIdx.x * 256 + threadIdx.x;
  int v = (i < n) ? in[i] : 0;
  sh[threadIdx.x] = v;
  __syncthreads();
#pragma unroll
  for (int off = 1; off < 256; off <<= 1) {
    int t = (threadIdx.x >= off) ? sh[threadIdx.x - off] : 0;
    __syncthreads();
    sh[threadIdx.x] += t;
    __syncthreads();
  }
  if (i < n) out[i] = sh[threadIdx.x] - v;  // exclusive
  if (threadIdx.x == 255) bsums[blockIdx.x] = sh[255];
}

__global__ __launch_bounds__(256)
void scan_bsums_k(int* bsums, int nb) {
  __shared__ int sh[256];
  int v = (threadIdx.x < nb) ? bsums[threadIdx.x] : 0;
  sh[threadIdx.x] = v;
  __syncthreads();
#pragma unroll
  for (int off = 1; off < 256; off <<= 1) {
    int t = (threadIdx.x >= off) ? sh[threadIdx.x - off] : 0;
    __syncthreads();
    sh[threadIdx.x] += t;
    __syncthreads();
  }
  if (threadIdx.x < nb) bsums[threadIdx.x] = sh[threadIdx.x] - v;
}

__global__ __launch_bounds__(256)
void add_off_k(int* __restrict__ out, const int* __restrict__ bsums, int n) {
  int i = blockIdx.x * 256 + threadIdx.x;
  if (i < n) out[i] += bsums[blockIdx.x];
  if (i == 0) out[n] = EE;
}

__global__ __launch_bounds__(256)
void fill_k(const int* __restrict__ src, const int* __restrict__ dst,
            const int* __restrict__ rowptr, int* __restrict__ cnt,
            int* __restrict__ csrsrc) {
  int e = blockIdx.x * 256 + threadIdx.x;
  if (e >= EE) return;
  int d = dst[e];
  int p = rowptr[d] + atomicAdd(&cnt[d], 1);
  csrsrc[p] = src[e];
}

// ---------------------------------------------------------------------------
// GAT aggregate, both relations fused. One wave per dst node; online softmax;
// lane owns feature pair (2*lane, 2*lane+1), both inside head lane>>3.
// 1-deep prefetch of (src, el, feat) overlaps gathers with compute.
// ---------------------------------------------------------------------------
__device__ __forceinline__ float2 agg_rel(const __half2* __restrict__ feat,
                                          const float* __restrict__ el,
                                          float er_h,
                                          const int* __restrict__ csr,
                                          int beg, int end, int lane, int head) {
  float m = -INFINITY, lsum = 0.f, a0 = 0.f, a1 = 0.f;
  if (beg < end) {
    int s = csr[beg];
    float ev = el[(size_t)s * 8 + head];
    __half2 f = feat[(size_t)s * 64 + lane];
    for (int idx = beg; idx < end; ++idx) {
      int s_nx = 0; float e_nx = 0.f;
      __half2 f_nx = __floats2half2_rn(0.f, 0.f);
      if (idx + 1 < end) {  // wave-uniform branch
        s_nx = csr[idx + 1];
        e_nx = el[(size_t)s_nx * 8 + head];
        f_nx = feat[(size_t)s_nx * 64 + lane];
      }
      float e = ev + er_h;
      e = (e > 0.f) ? e : 0.2f * e;            // leaky_relu 0.2
      float mn = fmaxf(m, e);
      float scl = __expf(m - mn);              // first iter: exp(-inf)=0
      float p = __expf(e - mn);
      float2 fv = __half22float2(f);
      lsum = lsum * scl + p;
      a0 = a0 * scl + p * fv.x;
      a1 = a1 * scl + p * fv.y;
      m = mn;
      s = s_nx; ev = e_nx; f = f_nx;
    }
  }
  float inv = (lsum > 0.f) ? 1.f / lsum : 0.f;  // isolated node -> rst = 0
  return make_float2(a0 * inv, a1 * inv);
}

__global__ __launch_bounds__(256)
void gat_agg_fused_k(const __half2* __restrict__ feat0,
                     const __half2* __restrict__ feat1,
                     const float* __restrict__ el0, const float* __restrict__ er0,
                     const float* __restrict__ el1, const float* __restrict__ er1,
                     const int* __restrict__ rp0, const int* __restrict__ cs0,
                     const int* __restrict__ rp1, const int* __restrict__ cs1,
                     const float* __restrict__ b0, const float* __restrict__ b1,
                     float* __restrict__ h1) {
  int n = blockIdx.x * 4 + (threadIdx.x >> 6);
  if (n >= NN) return;
  int lane = threadIdx.x & 63;
  int head = lane >> 3;
  float2 r0 = agg_rel(feat0, el0, er0[(size_t)n * 8 + head], cs0,
                      rp0[n], rp0[n + 1], lane, head);
  float2 r1 = agg_rel(feat1, el1, er1[(size_t)n * 8 + head], cs1,
                      rp1[n], rp1[n + 1], lane, head);
  float t0 = r0.x + b0[lane * 2] + r1.x + b1[lane * 2];
  float t1 = r0.y + b0[lane * 2 + 1] + r1.y + b1[lane * 2 + 1];
  t0 = (t0 > 0.f) ? t0 : 0.01f * t0;           // leaky_relu 0.01
  t1 = (t1 > 0.f) ? t1 : 0.01f * t1;
  float2* h2p = (float2*)h1 + (size_t)n * 64 + lane;
  float2 h = *h2p;
  h.x += t0; h.y += t1;
  *h2p = h;
}

// ---------------------------------------------------------------------------
extern "C" void kernel_launch(void* const* d_in, const int* in_sizes, int n_in,
                              void* d_out, int out_size, void* d_ws,
                              size_t ws_size, hipStream_t stream) {
  const float* inputs = (const float*)d_in[0];
  const int* src = (const int*)d_in[1];
  const int* dst = (const int*)d_in[2];
  const float* ew1 = (const float*)d_in[3];
  const float* eg = (const float*)d_in[4];
  const float* eb = (const float*)d_in[5];
  const float* ew2 = (const float*)d_in[6];
  const float* gfc = (const float*)d_in[7];
  const float* gal = (const float*)d_in[8];
  const float* gar = (const float*)d_in[9];
  const float* gb = (const float*)d_in[10];
  const float* dw1 = (const float*)d_in[11];
  const float* dg = (const float*)d_in[12];
  const float* db = (const float*)d_in[13];
  const float* dw2 = (const float*)d_in[14];
  float* out = (float*)d_out;

  // workspace layout (~65 MB)
  float* h1 = (float*)d_ws;                         // N*128 fp32
  float* ybuf = h1 + (size_t)NN * HIDF;             // N*128 fp32 (MLP phases)
  __half* feat0h = (__half*)ybuf;                   // aliases ybuf in GAT phase
  __half* feat1h = feat0h + (size_t)NN * HIDF;      // (2x N*128 half == ybuf)
  float* el0 = ybuf + (size_t)NN * HIDF;
  float* er0 = el0 + (size_t)NN * NHEAD;
  float* el1 = er0 + (size_t)NN * NHEAD;
  float* er1 = el1 + (size_t)NN * NHEAD;
  float* stats = er1 + (size_t)NN * NHEAD;          // 512 floats
  int* rowptr0 = (int*)(stats + 512);
  int* rowptr1 = rowptr0 + (NN + 1);
  int* csr0 = rowptr1 + (NN + 1);
  int* csr1 = csr0 + EE;
  int* cnt = csr1 + EE;
  int* bsums = cnt + NN;  // 256 ints
  int* rowptr[2] = {rowptr0, rowptr1};
  int* csr[2] = {csr0, csr1};

  const int SCB = (NN + 255) / 256;   // 196
  const int EGB = (EE + 255) / 256;   // 3125
  const int GB = (NN + 127) / 128;    // 391

  // ---- CSR build per relation (graph static across layers) ----
  for (int r = 0; r < 2; ++r) {
    hipMemsetAsync(cnt, 0, NN * sizeof(int), stream);
    hist_k<<<EGB, 256, 0, stream>>>(dst + (size_t)r * EE, cnt);
    scan_block_k<<<SCB, 256, 0, stream>>>(cnt, rowptr[r], bsums, NN);
    scan_bsums_k<<<1, 256, 0, stream>>>(bsums, SCB);
    add_off_k<<<SCB, 256, 0, stream>>>(rowptr[r], bsums, NN);
    hipMemsetAsync(cnt, 0, NN * sizeof(int), stream);
    fill_k<<<EGB, 256, 0, stream>>>(src + (size_t)r * EE, dst + (size_t)r * EE,
                                    rowptr[r], cnt, csr[r]);
  }

  // ---- embed MLP: h = relu(bn(x@w1)); h1 = h@w2 + h ----
  gemm_k<64, 128, 8, float><<<GB, 256, 0, stream>>>(inputs, ew1, nullptr, ybuf, NN);
  hipMemsetAsync(stats, 0, 512 * sizeof(float), stream);
  bn_stats_k<<<(NN + 63) / 64, 256, 0, stream>>>(ybuf, stats, NN);
  bn_final_k<<<1, 128, 0, stream>>>(stats, eg, eb);
  bn_apply_k<<<(NN * 32 + 255) / 256, 256, 0, stream>>>(ybuf, stats, ybuf, NN);
  gemm_k<128, 128, 8, float><<<GB, 256, 0, stream>>>(ybuf, ew2, ybuf, h1, NN);

  // ---- 4 GAT layers, 2 relations fused per layer ----
  for (int l = 0; l < 4; ++l) {
    const float* W0 = gfc + (size_t)(l * 2 + 0) * HIDF * HIDF;
    const float* W1 = gfc + (size_t)(l * 2 + 1) * HIDF * HIDF;
    gemm_k<128, 128, 8, __half><<<GB, 256, 0, stream>>>(h1, W0, nullptr, feat0h, NN);
    gemm_k<128, 128, 8, __half><<<GB, 256, 0, stream>>>(h1, W1, nullptr, feat1h, NN);
    eler_k<<<(NN * 8 + 255) / 256, 256, 0, stream>>>(
        (const __half2*)feat0h, gal + (size_t)(l * 2 + 0) * HIDF,
        gar + (size_t)(l * 2 + 0) * HIDF, el0, er0);
    eler_k<<<(NN * 8 + 255) / 256, 256, 0, stream>>>(
        (const __half2*)feat1h, gal + (size_t)(l * 2 + 1) * HIDF,
        gar + (size_t)(l * 2 + 1) * HIDF, el1, er1);
    gat_agg_fused_k<<<NN / 4, 256, 0, stream>>>(
        (const __half2*)feat0h, (const __half2*)feat1h, el0, er0, el1, er1,
        rowptr[0], csr[0], rowptr[1], csr[1],
        gb + (size_t)(l * 2 + 0) * HIDF, gb + (size_t)(l * 2 + 1) * HIDF, h1);
  }

  // ---- decision MLP: out = relu(bn(h1@w1)) @ w2 ----
  gemm_k<128, 128, 8, float><<<GB, 256, 0, stream>>>(h1, dw1, nullptr, ybuf, NN);
  hipMemsetAsync(stats, 0, 512 * sizeof(float), stream);
  bn_stats_k<<<(NN + 63) / 64, 256, 0, stream>>>(ybuf, stats, NN);
  bn_final_k<<<1, 128, 0, stream>>>(stats, dg, db);
  bn_apply_k<<<(NN * 32 + 255) / 256, 256, 0, stream>>>(ybuf, stats, ybuf, NN);
  gemm_k<128, 32, 2, float><<<GB, 256, 0, stream>>>(ybuf, dw2, nullptr, out, NN);
}